// Round 10
// baseline (334.234 us; speedup 1.0000x reference)
//
#include <hip/hip_runtime.h>
#include <stdint.h>

#define NPTS (96*96*96)          // 884736
#define NP5  (NPTS*5)            // 4423680 entries (point,vertex)

// Dense lattice grid (interval arithmetic from fixed domain: z,y,x in [0,95],
// image in [0,1); incl. rank-adjust, r-offset, blur padding, +/-2 margin):
//   q0 in [-3,25], q1 in [-14,14], q2 in [-16,8], q3 in [-17,3]
#define GD1 33
#define GD2 29
#define GD3 25
#define GO0 5
#define GO1 16
#define GO2 18
#define GO3 19
#define GS3 5
#define GS2 (GD3*GS3)      // 125
#define GS1 (GD2*GS2)      // 3625
#define GS0 (GD1*GS1)      // 119625
#define GCELLS (31*GS0)    // 3708375
#define GCELLS1 (GCELLS+1) // + trash cell for (never-expected) OOB
#define GSSUM (GS0+GS1+GS2+GS3)  // 123380

#define LHS 2048           // block-local LDS hash slots (1280 entries -> load <=0.625)

struct BN { float w; int next; };   // bary weight + chain link (fallback path)
struct LatPt { int cell[5]; float w[5]; };

// Pack input_ channels into float4 per point (fallback path only)
__global__ void k_qpack(const float* __restrict__ input_, float4* __restrict__ qp)
{
  int n = blockIdx.x * blockDim.x + threadIdx.x;
  if (n >= NPTS) return;
  qp[n] = make_float4(input_[n], input_[NPTS + n], input_[2 * NPTS + n], input_[3 * NPTS + n]);
}

// Shared per-point lattice math macro producing rank[5], rem0i[4], b[]
#define LATTICE_MATH(n)                                                        \
  int x = n % 96, y = (n / 96) % 96, z = n / (96 * 96);                        \
  float cf[4];                                                                 \
  cf[0] = ((float)z / 5.0f) * 2.8867513459481287f;                             \
  cf[1] = ((float)y / 5.0f) * 1.6666666666666667f;                             \
  cf[2] = ((float)x / 5.0f) * 1.1785113019775793f;                             \
  cf[3] = (imgv / 0.25f) * 0.9128709291752769f;                                \
  float elev[5];                                                               \
  float sm = 0.f;                                                              \
  _Pragma("unroll")                                                            \
  for (int i = 4; i >= 1; --i){ float c = cf[i-1]; elev[i] = sm - (float)i * c; sm += c; } \
  elev[0] = sm;                                                                \
  float rem0[5]; float sumrd_f = 0.f;                                          \
  _Pragma("unroll")                                                            \
  for (int i = 0; i < 5; i++){ float rd = rintf(elev[i] / 5.0f); rem0[i] = rd * 5.0f; sumrd_f += rd; } \
  int sum_rd = (int)sumrd_f;                                                   \
  float diff[5];                                                               \
  _Pragma("unroll")                                                            \
  for (int i = 0; i < 5; i++) diff[i] = elev[i] - rem0[i];                     \
  int rank[5];                                                                 \
  _Pragma("unroll")                                                            \
  for (int i = 0; i < 5; i++){                                                 \
    int r = 0;                                                                 \
    _Pragma("unroll")                                                          \
    for (int j = 0; j < 5; j++){                                               \
      r += (diff[j] > diff[i] || (diff[j] == diff[i] && j < i)) ? 1 : 0;       \
    }                                                                          \
    rank[i] = r + sum_rd;                                                      \
  }                                                                            \
  _Pragma("unroll")                                                            \
  for (int i = 0; i < 5; i++){                                                 \
    if (rank[i] < 0)      { rank[i] += 5; rem0[i] += 5.0f; }                   \
    else if (rank[i] > 4) { rank[i] -= 5; rem0[i] -= 5.0f; }                   \
  }                                                                            \
  float b[6] = {0.f,0.f,0.f,0.f,0.f,0.f};                                      \
  _Pragma("unroll")                                                            \
  for (int i = 0; i < 5; i++){                                                 \
    float v = (elev[i] - rem0[i]) / 5.0f;                                      \
    b[4 - rank[i]] += v;                                                       \
    b[5 - rank[i]] -= v;                                                       \
  }                                                                            \
  b[0] += 1.0f + b[5];                                                         \
  int rem0i[4];                                                                \
  _Pragma("unroll")                                                            \
  for (int i = 0; i < 4; i++) rem0i[i] = (int)rem0[i];

// Dense-path per-point result: 5 cells + 5 weights (shared by build & slice —
// single implementation keeps the fp32 arithmetic bit-identical).
__device__ __forceinline__ LatPt lat_compute(int n, float imgv)
{
  LATTICE_MATH(n)
  LatPt p;
  #pragma unroll
  for (int r = 0; r < 5; r++){
    int q0 = (rem0i[0] / 5) - (rank[0] < 5 - r ? 0 : 1) + GO0;
    int q1 = (rem0i[1] / 5) - (rank[1] < 5 - r ? 0 : 1) + GO1;
    int q2 = (rem0i[2] / 5) - (rank[2] < 5 - r ? 0 : 1) + GO2;
    int q3 = (rem0i[3] / 5) - (rank[3] < 5 - r ? 0 : 1) + GO3;
    int cell = (((q0 * GD1 + q1) * GD2 + q2) * GD3 + q3) * 5 + r;
    if ((unsigned)cell >= (unsigned)GCELLS) cell = GCELLS;
    p.cell[r] = cell;
    p.w[r] = b[r];
  }
  return p;
}

// ====================== PATH A: LDS VALUE AGGREGATION ======================

// Phase 1: per-block LDS hash accumulates w*(q0..q3,1) per distinct cell via
// LDS float atomics; emission writes ONE pre-summed node per distinct cell
// (single global atomicExch splice). Nodes are SoA: nxt / wq03 / w4.
__global__ void k_build_agg(const float* __restrict__ image,
                            const float* __restrict__ input_,
                            int* __restrict__ head,
                            int* __restrict__ nxt,
                            float4* __restrict__ wq03,
                            float* __restrict__ w4a)
{
  __shared__ int   ls_cell[LHS];
  __shared__ float ls_wq[LHS * 5];
  __shared__ int   ls_cnt;

  int tid = threadIdx.x;
  #pragma unroll
  for (int i = 0; i < LHS / 256; i++){
    ls_cell[tid + 256 * i] = -1;
    #pragma unroll
    for (int c = 0; c < 5; c++) ls_wq[(tid + 256 * i) * 5 + c] = 0.f;
  }
  if (tid == 0) ls_cnt = 0;
  __syncthreads();

  int n = blockIdx.x * 256 + tid;
  float q0 = input_[n], q1 = input_[NPTS + n], q2 = input_[2 * NPTS + n], q3 = input_[3 * NPTS + n];
  LatPt P = lat_compute(n, image[n]);

  #pragma unroll
  for (int r = 0; r < 5; r++){
    int cell = P.cell[r];
    unsigned int h = ((unsigned int)cell * 2654435761u) & (LHS - 1);
    while (true){
      int prev = atomicCAS(&ls_cell[h], -1, cell);
      if (prev == -1 || prev == cell) break;
      h = (h + 1) & (LHS - 1);
    }
    float w = P.w[r];
    atomicAdd(&ls_wq[h * 5 + 0], w * q0);
    atomicAdd(&ls_wq[h * 5 + 1], w * q1);
    atomicAdd(&ls_wq[h * 5 + 2], w * q2);
    atomicAdd(&ls_wq[h * 5 + 3], w * q3);
    atomicAdd(&ls_wq[h * 5 + 4], w);
  }
  __syncthreads();

  int blockBase = blockIdx.x * 1280;
  for (int i = tid; i < LHS; i += 256){
    int cell = ls_cell[i];
    if (cell < 0) continue;
    int li = atomicAdd(&ls_cnt, 1);       // LDS counter: compact node index
    int node = blockBase + li;
    int old = atomicExch(&head[cell], node);
    nxt[node]  = old;
    wq03[node] = make_float4(ls_wq[i * 5 + 0], ls_wq[i * 5 + 1], ls_wq[i * 5 + 2], ls_wq[i * 5 + 3]);
    w4a[node]  = ls_wq[i * 5 + 4];
  }
}

// Phase 2: gather — walk short node chains (pre-summed per block), no value
// indirection. Emits occupancy bitmap via wave ballot.
__global__ void k_gather_agg(const int* __restrict__ head,
                             const int* __restrict__ nxt,
                             const float4* __restrict__ wq03,
                             const float* __restrict__ w4a,
                             float* __restrict__ vals,
                             unsigned int* __restrict__ bitmap)
{
  int c = blockIdx.x * blockDim.x + threadIdx.x;
  int e = -1;
  if (c < GCELLS1) e = head[c];
  bool occ = (e >= 0);
  unsigned long long mask = __ballot(occ);
  int lane = threadIdx.x & 63;
  if (lane == 0)       bitmap[c >> 5] = (unsigned int)(mask & 0xffffffffu);
  else if (lane == 32) bitmap[c >> 5] = (unsigned int)(mask >> 32);
  if (c >= GCELLS1) return;

  float s0 = 0.f, s1 = 0.f, s2 = 0.f, s3 = 0.f, s4 = 0.f;
  while (e >= 0){
    int en = nxt[e];              // dependent 4B load issues first
    float4 wq = wq03[e];
    float w4 = w4a[e];
    s0 += wq.x; s1 += wq.y; s2 += wq.z; s3 += wq.w; s4 += w4;
    e = en;
  }
  float* v = vals + (size_t)c * 5;
  v[0] = s0; v[1] = s1; v[2] = s2; v[3] = s3; v[4] = s4;
}

// ====================== PATH B (fallback): R8 scheme ======================

__global__ void k_build_lds(const float* __restrict__ image,
                            int* __restrict__ head,
                            BN* __restrict__ bnext)
{
  __shared__ int ls_cell[LHS];
  __shared__ int ls_head[LHS];

  int tid = threadIdx.x;
  #pragma unroll
  for (int i = 0; i < LHS / 256; i++){
    ls_cell[tid + 256 * i] = -1;
    ls_head[tid + 256 * i] = -1;
  }
  __syncthreads();

  int n = blockIdx.x * 256 + tid;
  LatPt P = lat_compute(n, image[n]);
  int blockBase = blockIdx.x * 1280;

  int lold[5]; unsigned int hs[5];
  #pragma unroll
  for (int r = 0; r < 5; r++){
    int cell = P.cell[r];
    unsigned int h = ((unsigned int)cell * 2654435761u) & (LHS - 1);
    while (true){
      int prev = atomicCAS(&ls_cell[h], -1, cell);
      if (prev == -1 || prev == cell) break;
      h = (h + 1) & (LHS - 1);
    }
    hs[r] = h;
    lold[r] = atomicExch(&ls_head[h], tid * 5 + r);
  }
  __syncthreads();

  #pragma unroll
  for (int r = 0; r < 5; r++){
    int e = blockBase + tid * 5 + r;
    int nxt2;
    if (lold[r] < 0){
      int lhead = ls_head[hs[r]];
      nxt2 = atomicExch(&head[P.cell[r]], blockBase + lhead);
    } else {
      nxt2 = blockBase + lold[r];
    }
    BN bn; bn.w = P.w[r]; bn.next = nxt2;
    bnext[e] = bn;
  }
}

__global__ void k_gather_d(const int* __restrict__ head,
                           const BN* __restrict__ bnext,
                           const float4* __restrict__ qp,
                           float* __restrict__ vals,
                           unsigned int* __restrict__ bitmap)
{
  int c = blockIdx.x * blockDim.x + threadIdx.x;
  int e = -1;
  if (c < GCELLS1) e = head[c];
  bool occ = (e >= 0);
  unsigned long long mask = __ballot(occ);
  int lane = threadIdx.x & 63;
  if (lane == 0)       bitmap[c >> 5] = (unsigned int)(mask & 0xffffffffu);
  else if (lane == 32) bitmap[c >> 5] = (unsigned int)(mask >> 32);
  if (c >= GCELLS1) return;

  float s0 = 0.f, s1 = 0.f, s2 = 0.f, s3 = 0.f, s4 = 0.f;
  while (e >= 0){
    BN bn = bnext[e];
    float4 q = qp[e / 5];
    s0 += bn.w * q.x; s1 += bn.w * q.y; s2 += bn.w * q.z; s3 += bn.w * q.w; s4 += bn.w;
    e = bn.next;
  }
  float* v = vals + (size_t)c * 5;
  v[0] = s0; v[1] = s1; v[2] = s2; v[3] = s3; v[4] = s4;
}

// ====================== SHARED: blur + slice ======================

__global__ void k_blur_d(const unsigned int* __restrict__ bitmap,
                         const float* __restrict__ vin,
                         float* __restrict__ vout,
                         int dPa, int dPb, int dMa, int dMb, int zfill)
{
  int c = blockIdx.x * blockDim.x + threadIdx.x;
  if (c >= GCELLS) return;
  unsigned int w = bitmap[c >> 5];
  if (!((w >> (c & 31)) & 1u)){
    if (zfill){
      float* vo = vout + (size_t)c * 5;
      vo[0] = 0.f; vo[1] = 0.f; vo[2] = 0.f; vo[3] = 0.f; vo[4] = 0.f;
    }
    return;
  }
  int r = c % 5;
  int p1 = c + (r == 4 ? dPb : dPa);
  int p2 = c + (r == 0 ? dMb : dMa);
  float* vo = vout + (size_t)c * 5;
  const float* va = vin + (size_t)c * 5;
  const float* n1 = vin + (size_t)p1 * 5;  // empty neighbors hold zeros
  const float* n2 = vin + (size_t)p2 * 5;
  #pragma unroll
  for (int ch = 0; ch < 5; ch++)
    vo[ch] = 0.5f * va[ch] + 0.25f * (n1[ch] + n2[ch]);
}

__global__ void k_slice_d(const float* __restrict__ image,
                          const float* __restrict__ vals,
                          float* __restrict__ out)
{
  int n = blockIdx.x * blockDim.x + threadIdx.x;
  if (n >= NPTS) return;
  LatPt P = lat_compute(n, image[n]);

  float s0 = 0.f, s1 = 0.f, s2 = 0.f, s3 = 0.f, s4 = 0.f;
  #pragma unroll
  for (int r = 0; r < 5; r++){
    float w = P.w[r];
    const float* v = vals + (size_t)P.cell[r] * 5;
    s0 += w * v[0]; s1 += w * v[1]; s2 += w * v[2]; s3 += w * v[3]; s4 += w * v[4];
  }
  float denom = s4 + 2.2204460492503131e-16f;
  out[n]            = s0 / denom;
  out[NPTS + n]     = s1 / denom;
  out[2 * NPTS + n] = s2 / denom;
  out[3 * NPTS + n] = s3 / denom;
}

// ============================ HOST ============================

extern "C" void kernel_launch(void* const* d_in, const int* in_sizes, int n_in,
                              void* d_out, int out_size, void* d_ws, size_t ws_size,
                              hipStream_t stream)
{
  const float* input_ = (const float*)d_in[0];
  const float* image  = (const float*)d_in[1];
  float* out = (float*)d_out;
  char* ws = (char*)d_ws;

  const int NB = (NPTS + 255) / 256;
  const int CB = (GCELLS1 + 255) / 256;
  const size_t BMWORDS = (size_t)CB * 8;
  const int Sj[5] = { GS0, GS1, GS2, GS3, 0 };

  // ---- Path A workspace: node SoA (pre-summed per block-cell) ----
  // KEY: valsB is ALIASED over the node arrays (nxt/wq03/w4a). Nodes are dead
  // after k_gather_agg; valsB is first written in blur pass j=0, which zfills
  // empty cells, so stale node bytes beneath are harmless.  ~196 MB total.
  {
    size_t o = 0;
    size_t off_head = o; o += (size_t)GCELLS1 * 4;      o = (o + 255) & ~(size_t)255;
    size_t off_bm   = o; o += BMWORDS * 4;              o = (o + 255) & ~(size_t)255;
    size_t off_node = o;                                 // node region start
    size_t off_nxt  = o; o += (size_t)NP5 * 4;          o = (o + 255) & ~(size_t)255;
    size_t off_wq   = o; o += (size_t)NP5 * 16;         o = (o + 255) & ~(size_t)255;
    size_t off_w4   = o; o += (size_t)NP5 * 4;          o = (o + 255) & ~(size_t)255;
    size_t node_end = o;
    size_t off_vA   = o; o += (size_t)GCELLS1 * 5 * 4;
    size_t vB_need  = (size_t)GCELLS1 * 5 * 4;
    // valsB aliases the node region (node region is 106 MB >= 74 MB needed)
    size_t off_vB   = off_node;
    size_t need = o;
    if (node_end - off_node < vB_need){ off_vB = o; need = o + vB_need; } // paranoia
    if (need <= ws_size){
      int*          head   = (int*)(ws + off_head);
      unsigned int* bitmap = (unsigned int*)(ws + off_bm);
      int*          nxt    = (int*)(ws + off_nxt);
      float4*       wq03   = (float4*)(ws + off_wq);
      float*        w4a    = (float*)(ws + off_w4);
      float*        valsA  = (float*)(ws + off_vA);
      float*        valsB  = (float*)(ws + off_vB);

      hipMemsetAsync(head, 0xFF, (size_t)GCELLS1 * 4, stream);

      k_build_agg<<<NB, 256, 0, stream>>>(image, input_, head, nxt, wq03, w4a);
      k_gather_agg<<<CB, 256, 0, stream>>>(head, nxt, wq03, w4a, valsA, bitmap);

      float* vin = valsA; float* vout = valsB;
      for (int j = 0; j < 5; j++){
        int dPa = 1 - Sj[j];
        int dPb = GSSUM - Sj[j] - 4;
        int dMa = Sj[j] - 1;
        int dMb = Sj[j] - GSSUM + 4;
        k_blur_d<<<CB, 256, 0, stream>>>(bitmap, vin, vout, dPa, dPb, dMa, dMb,
                                         (j == 0) ? 1 : 0);
        float* t = vin; vin = vout; vout = t;
      }

      k_slice_d<<<NB, 256, 0, stream>>>(image, vin, out);
      return;
    }
  }

  // ---- Path B fallback: R8 per-entry chains ----
  size_t o = 0;
  size_t off_head  = o; o += (size_t)GCELLS1 * 4;      o = (o + 255) & ~(size_t)255;
  size_t off_bm    = o; o += BMWORDS * 4;              o = (o + 255) & ~(size_t)255;
  size_t off_bnext = o; o += (size_t)NP5 * 8;          o = (o + 255) & ~(size_t)255;
  size_t off_qp    = o; o += (size_t)NPTS * 16;        o = (o + 255) & ~(size_t)255;
  size_t off_vA    = o; o += (size_t)GCELLS1 * 5 * 4;  o = (o + 255) & ~(size_t)255;
  size_t off_vB    = o; o += (size_t)GCELLS1 * 5 * 4;

  int*          head   = (int*)(ws + off_head);
  unsigned int* bitmap = (unsigned int*)(ws + off_bm);
  BN*           bnext  = (BN*)(ws + off_bnext);
  float4*       qp     = (float4*)(ws + off_qp);
  float*        valsA  = (float*)(ws + off_vA);
  float*        valsB  = (float*)(ws + off_vB);

  hipMemsetAsync(head, 0xFF, (size_t)GCELLS1 * 4, stream);

  k_qpack<<<NB, 256, 0, stream>>>(input_, qp);
  k_build_lds<<<NB, 256, 0, stream>>>(image, head, bnext);
  k_gather_d<<<CB, 256, 0, stream>>>(head, bnext, qp, valsA, bitmap);

  float* vin = valsA; float* vout = valsB;
  for (int j = 0; j < 5; j++){
    int dPa = 1 - Sj[j];
    int dPb = GSSUM - Sj[j] - 4;
    int dMa = Sj[j] - 1;
    int dMb = Sj[j] - GSSUM + 4;
    k_blur_d<<<CB, 256, 0, stream>>>(bitmap, vin, vout, dPa, dPb, dMa, dMb,
                                     (j == 0) ? 1 : 0);
    float* t = vin; vin = vout; vout = t;
  }

  k_slice_d<<<NB, 256, 0, stream>>>(image, vin, out);
}

// Round 11
// 236.585 us; speedup vs baseline: 1.4127x; 1.4127x over previous
//
#include <hip/hip_runtime.h>
#include <stdint.h>

#define NPTS (96*96*96)          // 884736
#define NP5  (NPTS*5)            // 4423680 entries (point,vertex)

// Dense lattice grid (interval arithmetic from fixed domain: z,y,x in [0,95],
// image in [0,1); incl. rank-adjust, r-offset, blur padding, +/-2 margin):
//   q0 in [-3,25], q1 in [-14,14], q2 in [-16,8], q3 in [-17,3]
#define GD1 33
#define GD2 29
#define GD3 25
#define GO0 5
#define GO1 16
#define GO2 18
#define GO3 19
#define GS3 5
#define GS2 (GD3*GS3)      // 125
#define GS1 (GD2*GS2)      // 3625
#define GS0 (GD1*GS1)      // 119625
#define GCELLS (31*GS0)    // 3708375
#define GCELLS1 (GCELLS+1) // + trash cell for (never-expected) OOB
#define GSSUM (GS0+GS1+GS2+GS3)  // 123380

#define LHS 2048           // block-local LDS hash slots (1280 entries -> load <=0.625)

struct BN { float w; int next; };   // bary weight + chain link (fallback path)
struct NW { int next; float w4; };  // node: chain link + weight-sum, 8B
struct LatPt { int cell[5]; float w[5]; };

// Pack input_ channels into float4 per point (fallback path only)
__global__ void k_qpack(const float* __restrict__ input_, float4* __restrict__ qp)
{
  int n = blockIdx.x * blockDim.x + threadIdx.x;
  if (n >= NPTS) return;
  qp[n] = make_float4(input_[n], input_[NPTS + n], input_[2 * NPTS + n], input_[3 * NPTS + n]);
}

// Shared per-point lattice math macro producing rank[5], rem0i[4], b[]
#define LATTICE_MATH(n)                                                        \
  int x = n % 96, y = (n / 96) % 96, z = n / (96 * 96);                        \
  float cf[4];                                                                 \
  cf[0] = ((float)z / 5.0f) * 2.8867513459481287f;                             \
  cf[1] = ((float)y / 5.0f) * 1.6666666666666667f;                             \
  cf[2] = ((float)x / 5.0f) * 1.1785113019775793f;                             \
  cf[3] = (imgv / 0.25f) * 0.9128709291752769f;                                \
  float elev[5];                                                               \
  float sm = 0.f;                                                              \
  _Pragma("unroll")                                                            \
  for (int i = 4; i >= 1; --i){ float c = cf[i-1]; elev[i] = sm - (float)i * c; sm += c; } \
  elev[0] = sm;                                                                \
  float rem0[5]; float sumrd_f = 0.f;                                          \
  _Pragma("unroll")                                                            \
  for (int i = 0; i < 5; i++){ float rd = rintf(elev[i] / 5.0f); rem0[i] = rd * 5.0f; sumrd_f += rd; } \
  int sum_rd = (int)sumrd_f;                                                   \
  float diff[5];                                                               \
  _Pragma("unroll")                                                            \
  for (int i = 0; i < 5; i++) diff[i] = elev[i] - rem0[i];                     \
  int rank[5];                                                                 \
  _Pragma("unroll")                                                            \
  for (int i = 0; i < 5; i++){                                                 \
    int r = 0;                                                                 \
    _Pragma("unroll")                                                          \
    for (int j = 0; j < 5; j++){                                               \
      r += (diff[j] > diff[i] || (diff[j] == diff[i] && j < i)) ? 1 : 0;       \
    }                                                                          \
    rank[i] = r + sum_rd;                                                      \
  }                                                                            \
  _Pragma("unroll")                                                            \
  for (int i = 0; i < 5; i++){                                                 \
    if (rank[i] < 0)      { rank[i] += 5; rem0[i] += 5.0f; }                   \
    else if (rank[i] > 4) { rank[i] -= 5; rem0[i] -= 5.0f; }                   \
  }                                                                            \
  float b[6] = {0.f,0.f,0.f,0.f,0.f,0.f};                                      \
  _Pragma("unroll")                                                            \
  for (int i = 0; i < 5; i++){                                                 \
    float v = (elev[i] - rem0[i]) / 5.0f;                                      \
    b[4 - rank[i]] += v;                                                       \
    b[5 - rank[i]] -= v;                                                       \
  }                                                                            \
  b[0] += 1.0f + b[5];                                                         \
  int rem0i[4];                                                                \
  _Pragma("unroll")                                                            \
  for (int i = 0; i < 4; i++) rem0i[i] = (int)rem0[i];

// Dense-path per-point result: 5 cells + 5 weights (shared by build & slice —
// single implementation keeps the fp32 arithmetic bit-identical).
__device__ __forceinline__ LatPt lat_compute(int n, float imgv)
{
  LATTICE_MATH(n)
  LatPt p;
  #pragma unroll
  for (int r = 0; r < 5; r++){
    int q0 = (rem0i[0] / 5) - (rank[0] < 5 - r ? 0 : 1) + GO0;
    int q1 = (rem0i[1] / 5) - (rank[1] < 5 - r ? 0 : 1) + GO1;
    int q2 = (rem0i[2] / 5) - (rank[2] < 5 - r ? 0 : 1) + GO2;
    int q3 = (rem0i[3] / 5) - (rank[3] < 5 - r ? 0 : 1) + GO3;
    int cell = (((q0 * GD1 + q1) * GD2 + q2) * GD3 + q3) * 5 + r;
    if ((unsigned)cell >= (unsigned)GCELLS) cell = GCELLS;
    p.cell[r] = cell;
    p.w[r] = b[r];
  }
  return p;
}

// =============== PATH A: HYBRID CHAIN-BUILD + LDS-WALK AGGREGATION =========

// Phase 1a: R7-style LDS chain build (CAS + exch only, no float atomics),
// staging w per (point,vertex) and q per point in LDS.
// Phase 1b: per distinct cell, ONE thread walks the local chain with plain
// LDS reads, sums the 5 channels, and emits ONE pre-summed node with a
// single global atomicExch splice. Nodes are 2-stream SoA: nw(8B) + wq03(16B).
__global__ void k_build_hyb(const float* __restrict__ image,
                            const float* __restrict__ input_,
                            int* __restrict__ head,
                            NW* __restrict__ nw,
                            float4* __restrict__ wq03)
{
  __shared__ int   ls_cell[LHS];
  __shared__ int   ls_head[LHS];
  __shared__ int   ls_next[1280];
  __shared__ float ls_w[1280];
  __shared__ float ls_q[256 * 4];
  __shared__ int   ls_cnt;

  int tid = threadIdx.x;
  #pragma unroll
  for (int i = 0; i < LHS / 256; i++){
    ls_cell[tid + 256 * i] = -1;
    ls_head[tid + 256 * i] = -1;
  }
  if (tid == 0) ls_cnt = 0;
  __syncthreads();

  int n = blockIdx.x * 256 + tid;
  ls_q[tid * 4 + 0] = input_[n];
  ls_q[tid * 4 + 1] = input_[NPTS + n];
  ls_q[tid * 4 + 2] = input_[2 * NPTS + n];
  ls_q[tid * 4 + 3] = input_[3 * NPTS + n];
  LatPt P = lat_compute(n, image[n]);

  #pragma unroll
  for (int r = 0; r < 5; r++){
    int cell = P.cell[r];
    unsigned int h = ((unsigned int)cell * 2654435761u) & (LHS - 1);
    while (true){
      int prev = atomicCAS(&ls_cell[h], -1, cell);
      if (prev == -1 || prev == cell) break;
      h = (h + 1) & (LHS - 1);
    }
    int e = tid * 5 + r;
    ls_w[e] = P.w[r];
    ls_next[e] = atomicExch(&ls_head[h], e);   // local chain push
  }
  __syncthreads();

  int blockBase = blockIdx.x * 1280;
  for (int i = tid; i < LHS; i += 256){
    int cell = ls_cell[i];
    if (cell < 0) continue;
    float s0 = 0.f, s1 = 0.f, s2 = 0.f, s3 = 0.f, s4 = 0.f;
    int e = ls_head[i];
    while (e >= 0){
      float w = ls_w[e];
      int pt = e / 5;
      s0 += w * ls_q[pt * 4 + 0];
      s1 += w * ls_q[pt * 4 + 1];
      s2 += w * ls_q[pt * 4 + 2];
      s3 += w * ls_q[pt * 4 + 3];
      s4 += w;
      e = ls_next[e];
    }
    int li = atomicAdd(&ls_cnt, 1);      // LDS counter: compact node index
    int node = blockBase + li;
    int old = atomicExch(&head[cell], node);
    NW a; a.next = old; a.w4 = s4;
    nw[node] = a;
    wq03[node] = make_float4(s0, s1, s2, s3);
  }
}

// Phase 2: gather — walk short pre-summed node chains. Emits occupancy bitmap.
__global__ void k_gather_agg(const int* __restrict__ head,
                             const NW* __restrict__ nw,
                             const float4* __restrict__ wq03,
                             float* __restrict__ vals,
                             unsigned int* __restrict__ bitmap)
{
  int c = blockIdx.x * blockDim.x + threadIdx.x;
  int e = -1;
  if (c < GCELLS1) e = head[c];
  bool occ = (e >= 0);
  unsigned long long mask = __ballot(occ);
  int lane = threadIdx.x & 63;
  if (lane == 0)       bitmap[c >> 5] = (unsigned int)(mask & 0xffffffffu);
  else if (lane == 32) bitmap[c >> 5] = (unsigned int)(mask >> 32);
  if (c >= GCELLS1) return;

  float s0 = 0.f, s1 = 0.f, s2 = 0.f, s3 = 0.f, s4 = 0.f;
  while (e >= 0){
    NW a = nw[e];                 // 8B: next + w4 in one load
    float4 wq = wq03[e];
    s0 += wq.x; s1 += wq.y; s2 += wq.z; s3 += wq.w; s4 += a.w4;
    e = a.next;
  }
  float* v = vals + (size_t)c * 5;
  v[0] = s0; v[1] = s1; v[2] = s2; v[3] = s3; v[4] = s4;
}

// ====================== PATH B (fallback): R8 scheme ======================

__global__ void k_build_lds(const float* __restrict__ image,
                            int* __restrict__ head,
                            BN* __restrict__ bnext)
{
  __shared__ int ls_cell[LHS];
  __shared__ int ls_head[LHS];

  int tid = threadIdx.x;
  #pragma unroll
  for (int i = 0; i < LHS / 256; i++){
    ls_cell[tid + 256 * i] = -1;
    ls_head[tid + 256 * i] = -1;
  }
  __syncthreads();

  int n = blockIdx.x * 256 + tid;
  LatPt P = lat_compute(n, image[n]);
  int blockBase = blockIdx.x * 1280;

  int lold[5]; unsigned int hs[5];
  #pragma unroll
  for (int r = 0; r < 5; r++){
    int cell = P.cell[r];
    unsigned int h = ((unsigned int)cell * 2654435761u) & (LHS - 1);
    while (true){
      int prev = atomicCAS(&ls_cell[h], -1, cell);
      if (prev == -1 || prev == cell) break;
      h = (h + 1) & (LHS - 1);
    }
    hs[r] = h;
    lold[r] = atomicExch(&ls_head[h], tid * 5 + r);
  }
  __syncthreads();

  #pragma unroll
  for (int r = 0; r < 5; r++){
    int e = blockBase + tid * 5 + r;
    int nxt2;
    if (lold[r] < 0){
      int lhead = ls_head[hs[r]];
      nxt2 = atomicExch(&head[P.cell[r]], blockBase + lhead);
    } else {
      nxt2 = blockBase + lold[r];
    }
    BN bn; bn.w = P.w[r]; bn.next = nxt2;
    bnext[e] = bn;
  }
}

__global__ void k_gather_d(const int* __restrict__ head,
                           const BN* __restrict__ bnext,
                           const float4* __restrict__ qp,
                           float* __restrict__ vals,
                           unsigned int* __restrict__ bitmap)
{
  int c = blockIdx.x * blockDim.x + threadIdx.x;
  int e = -1;
  if (c < GCELLS1) e = head[c];
  bool occ = (e >= 0);
  unsigned long long mask = __ballot(occ);
  int lane = threadIdx.x & 63;
  if (lane == 0)       bitmap[c >> 5] = (unsigned int)(mask & 0xffffffffu);
  else if (lane == 32) bitmap[c >> 5] = (unsigned int)(mask >> 32);
  if (c >= GCELLS1) return;

  float s0 = 0.f, s1 = 0.f, s2 = 0.f, s3 = 0.f, s4 = 0.f;
  while (e >= 0){
    BN bn = bnext[e];
    float4 q = qp[e / 5];
    s0 += bn.w * q.x; s1 += bn.w * q.y; s2 += bn.w * q.z; s3 += bn.w * q.w; s4 += bn.w;
    e = bn.next;
  }
  float* v = vals + (size_t)c * 5;
  v[0] = s0; v[1] = s1; v[2] = s2; v[3] = s3; v[4] = s4;
}

// ====================== SHARED: blur + slice ======================

__global__ void k_blur_d(const unsigned int* __restrict__ bitmap,
                         const float* __restrict__ vin,
                         float* __restrict__ vout,
                         int dPa, int dPb, int dMa, int dMb, int zfill)
{
  int c = blockIdx.x * blockDim.x + threadIdx.x;
  if (c >= GCELLS) return;
  unsigned int w = bitmap[c >> 5];
  if (!((w >> (c & 31)) & 1u)){
    if (zfill){
      float* vo = vout + (size_t)c * 5;
      vo[0] = 0.f; vo[1] = 0.f; vo[2] = 0.f; vo[3] = 0.f; vo[4] = 0.f;
    }
    return;
  }
  int r = c % 5;
  int p1 = c + (r == 4 ? dPb : dPa);
  int p2 = c + (r == 0 ? dMb : dMa);
  float* vo = vout + (size_t)c * 5;
  const float* va = vin + (size_t)c * 5;
  const float* n1 = vin + (size_t)p1 * 5;  // empty neighbors hold zeros
  const float* n2 = vin + (size_t)p2 * 5;
  #pragma unroll
  for (int ch = 0; ch < 5; ch++)
    vo[ch] = 0.5f * va[ch] + 0.25f * (n1[ch] + n2[ch]);
}

__global__ void k_slice_d(const float* __restrict__ image,
                          const float* __restrict__ vals,
                          float* __restrict__ out)
{
  int n = blockIdx.x * blockDim.x + threadIdx.x;
  if (n >= NPTS) return;
  LatPt P = lat_compute(n, image[n]);

  float s0 = 0.f, s1 = 0.f, s2 = 0.f, s3 = 0.f, s4 = 0.f;
  #pragma unroll
  for (int r = 0; r < 5; r++){
    float w = P.w[r];
    const float* v = vals + (size_t)P.cell[r] * 5;
    s0 += w * v[0]; s1 += w * v[1]; s2 += w * v[2]; s3 += w * v[3]; s4 += w * v[4];
  }
  float denom = s4 + 2.2204460492503131e-16f;
  out[n]            = s0 / denom;
  out[NPTS + n]     = s1 / denom;
  out[2 * NPTS + n] = s2 / denom;
  out[3 * NPTS + n] = s3 / denom;
}

// ============================ HOST ============================

extern "C" void kernel_launch(void* const* d_in, const int* in_sizes, int n_in,
                              void* d_out, int out_size, void* d_ws, size_t ws_size,
                              hipStream_t stream)
{
  const float* input_ = (const float*)d_in[0];
  const float* image  = (const float*)d_in[1];
  float* out = (float*)d_out;
  char* ws = (char*)d_ws;

  const int NB = (NPTS + 255) / 256;
  const int CB = (GCELLS1 + 255) / 256;
  const size_t BMWORDS = (size_t)CB * 8;
  const int Sj[5] = { GS0, GS1, GS2, GS3, 0 };

  // ---- Path A workspace (~196 MB): valsB ALIASED over the node arrays
  // (nw/wq03, 106 MB). Nodes are dead after k_gather_agg; valsB is first
  // written in blur pass j=0, which zfills empty cells.
  {
    size_t o = 0;
    size_t off_head = o; o += (size_t)GCELLS1 * 4;      o = (o + 255) & ~(size_t)255;
    size_t off_bm   = o; o += BMWORDS * 4;              o = (o + 255) & ~(size_t)255;
    size_t off_node = o;
    size_t off_nw   = o; o += (size_t)NP5 * 8;          o = (o + 255) & ~(size_t)255;
    size_t off_wq   = o; o += (size_t)NP5 * 16;         o = (o + 255) & ~(size_t)255;
    size_t node_end = o;
    size_t off_vA   = o; o += (size_t)GCELLS1 * 5 * 4;
    size_t vB_need  = (size_t)GCELLS1 * 5 * 4;
    size_t off_vB   = off_node;
    size_t need = o;
    if (node_end - off_node < vB_need){ off_vB = o; need = o + vB_need; } // paranoia
    if (need <= ws_size){
      int*          head   = (int*)(ws + off_head);
      unsigned int* bitmap = (unsigned int*)(ws + off_bm);
      NW*           nw     = (NW*)(ws + off_nw);
      float4*       wq03   = (float4*)(ws + off_wq);
      float*        valsA  = (float*)(ws + off_vA);
      float*        valsB  = (float*)(ws + off_vB);

      hipMemsetAsync(head, 0xFF, (size_t)GCELLS1 * 4, stream);

      k_build_hyb<<<NB, 256, 0, stream>>>(image, input_, head, nw, wq03);
      k_gather_agg<<<CB, 256, 0, stream>>>(head, nw, wq03, valsA, bitmap);

      float* vin = valsA; float* vout = valsB;
      for (int j = 0; j < 5; j++){
        int dPa = 1 - Sj[j];
        int dPb = GSSUM - Sj[j] - 4;
        int dMa = Sj[j] - 1;
        int dMb = Sj[j] - GSSUM + 4;
        k_blur_d<<<CB, 256, 0, stream>>>(bitmap, vin, vout, dPa, dPb, dMa, dMb,
                                         (j == 0) ? 1 : 0);
        float* t = vin; vin = vout; vout = t;
      }

      k_slice_d<<<NB, 256, 0, stream>>>(image, vin, out);
      return;
    }
  }

  // ---- Path B fallback: R8 per-entry chains ----
  size_t o = 0;
  size_t off_head  = o; o += (size_t)GCELLS1 * 4;      o = (o + 255) & ~(size_t)255;
  size_t off_bm    = o; o += BMWORDS * 4;              o = (o + 255) & ~(size_t)255;
  size_t off_bnext = o; o += (size_t)NP5 * 8;          o = (o + 255) & ~(size_t)255;
  size_t off_qp    = o; o += (size_t)NPTS * 16;        o = (o + 255) & ~(size_t)255;
  size_t off_vA    = o; o += (size_t)GCELLS1 * 5 * 4;  o = (o + 255) & ~(size_t)255;
  size_t off_vB    = o; o += (size_t)GCELLS1 * 5 * 4;

  int*          head   = (int*)(ws + off_head);
  unsigned int* bitmap = (unsigned int*)(ws + off_bm);
  BN*           bnext  = (BN*)(ws + off_bnext);
  float4*       qp     = (float4*)(ws + off_qp);
  float*        valsA  = (float*)(ws + off_vA);
  float*        valsB  = (float*)(ws + off_vB);

  hipMemsetAsync(head, 0xFF, (size_t)GCELLS1 * 4, stream);

  k_qpack<<<NB, 256, 0, stream>>>(input_, qp);
  k_build_lds<<<NB, 256, 0, stream>>>(image, head, bnext);
  k_gather_d<<<CB, 256, 0, stream>>>(head, bnext, qp, valsA, bitmap);

  float* vin = valsA; float* vout = valsB;
  for (int j = 0; j < 5; j++){
    int dPa = 1 - Sj[j];
    int dPb = GSSUM - Sj[j] - 4;
    int dMa = Sj[j] - 1;
    int dMb = Sj[j] - GSSUM + 4;
    k_blur_d<<<CB, 256, 0, stream>>>(bitmap, vin, vout, dPa, dPb, dMa, dMb,
                                     (j == 0) ? 1 : 0);
    float* t = vin; vin = vout; vout = t;
  }

  k_slice_d<<<NB, 256, 0, stream>>>(image, vin, out);
}

// Round 12
// 224.044 us; speedup vs baseline: 1.4918x; 1.0560x over previous
//
#include <hip/hip_runtime.h>
#include <hip/hip_fp16.h>
#include <stdint.h>

#define NPTS (96*96*96)          // 884736
#define NP5  (NPTS*5)            // 4423680 entries (point,vertex)

// Dense lattice grid (interval arithmetic from fixed domain: z,y,x in [0,95],
// image in [0,1); incl. rank-adjust, r-offset, blur padding, +/-2 margin):
//   q0 in [-3,25], q1 in [-14,14], q2 in [-16,8], q3 in [-17,3]
#define GD1 33
#define GD2 29
#define GD3 25
#define GO0 5
#define GO1 16
#define GO2 18
#define GO3 19
#define GS3 5
#define GS2 (GD3*GS3)      // 125
#define GS1 (GD2*GS2)      // 3625
#define GS0 (GD1*GS1)      // 119625
#define GCELLS (31*GS0)    // 3708375
#define GCELLS1 (GCELLS+1) // + trash cell for (never-expected) OOB
#define GSSUM (GS0+GS1+GS2+GS3)  // 123380

#define LHS 2048           // block-local LDS hash slots (1280 entries -> load <=0.625)

struct BN { float w; int next; };   // bary weight + chain link (fallback path)
struct LatPt { int cell[5]; float w[5]; };

// Pack input_ channels into float4 per point (fallback path only)
__global__ void k_qpack(const float* __restrict__ input_, float4* __restrict__ qp)
{
  int n = blockIdx.x * blockDim.x + threadIdx.x;
  if (n >= NPTS) return;
  qp[n] = make_float4(input_[n], input_[NPTS + n], input_[2 * NPTS + n], input_[3 * NPTS + n]);
}

// Shared per-point lattice math macro producing rank[5], rem0i[4], b[]
#define LATTICE_MATH(n)                                                        \
  int x = n % 96, y = (n / 96) % 96, z = n / (96 * 96);                        \
  float cf[4];                                                                 \
  cf[0] = ((float)z / 5.0f) * 2.8867513459481287f;                             \
  cf[1] = ((float)y / 5.0f) * 1.6666666666666667f;                             \
  cf[2] = ((float)x / 5.0f) * 1.1785113019775793f;                             \
  cf[3] = (imgv / 0.25f) * 0.9128709291752769f;                                \
  float elev[5];                                                               \
  float sm = 0.f;                                                              \
  _Pragma("unroll")                                                            \
  for (int i = 4; i >= 1; --i){ float c = cf[i-1]; elev[i] = sm - (float)i * c; sm += c; } \
  elev[0] = sm;                                                                \
  float rem0[5]; float sumrd_f = 0.f;                                          \
  _Pragma("unroll")                                                            \
  for (int i = 0; i < 5; i++){ float rd = rintf(elev[i] / 5.0f); rem0[i] = rd * 5.0f; sumrd_f += rd; } \
  int sum_rd = (int)sumrd_f;                                                   \
  float diff[5];                                                               \
  _Pragma("unroll")                                                            \
  for (int i = 0; i < 5; i++) diff[i] = elev[i] - rem0[i];                     \
  int rank[5];                                                                 \
  _Pragma("unroll")                                                            \
  for (int i = 0; i < 5; i++){                                                 \
    int r = 0;                                                                 \
    _Pragma("unroll")                                                          \
    for (int j = 0; j < 5; j++){                                               \
      r += (diff[j] > diff[i] || (diff[j] == diff[i] && j < i)) ? 1 : 0;       \
    }                                                                          \
    rank[i] = r + sum_rd;                                                      \
  }                                                                            \
  _Pragma("unroll")                                                            \
  for (int i = 0; i < 5; i++){                                                 \
    if (rank[i] < 0)      { rank[i] += 5; rem0[i] += 5.0f; }                   \
    else if (rank[i] > 4) { rank[i] -= 5; rem0[i] -= 5.0f; }                   \
  }                                                                            \
  float b[6] = {0.f,0.f,0.f,0.f,0.f,0.f};                                      \
  _Pragma("unroll")                                                            \
  for (int i = 0; i < 5; i++){                                                 \
    float v = (elev[i] - rem0[i]) / 5.0f;                                      \
    b[4 - rank[i]] += v;                                                       \
    b[5 - rank[i]] -= v;                                                       \
  }                                                                            \
  b[0] += 1.0f + b[5];                                                         \
  int rem0i[4];                                                                \
  _Pragma("unroll")                                                            \
  for (int i = 0; i < 4; i++) rem0i[i] = (int)rem0[i];

// Dense-path per-point result: 5 cells + 5 weights (shared by build & slice —
// single implementation keeps the fp32 arithmetic bit-identical).
__device__ __forceinline__ LatPt lat_compute(int n, float imgv)
{
  LATTICE_MATH(n)
  LatPt p;
  #pragma unroll
  for (int r = 0; r < 5; r++){
    int q0 = (rem0i[0] / 5) - (rank[0] < 5 - r ? 0 : 1) + GO0;
    int q1 = (rem0i[1] / 5) - (rank[1] < 5 - r ? 0 : 1) + GO1;
    int q2 = (rem0i[2] / 5) - (rank[2] < 5 - r ? 0 : 1) + GO2;
    int q3 = (rem0i[3] / 5) - (rank[3] < 5 - r ? 0 : 1) + GO3;
    int cell = (((q0 * GD1 + q1) * GD2 + q2) * GD3 + q3) * 5 + r;
    if ((unsigned)cell >= (unsigned)GCELLS) cell = GCELLS;
    p.cell[r] = cell;
    p.w[r] = b[r];
  }
  return p;
}

// =============== PATH A: HYBRID CHAIN-BUILD + LDS-WALK AGGREGATION =========
// Node = ONE 16B record: { next:int, q01:half2, q23:half2, w4:float }.
// w4 stays fp32 (exact denominators); fp16 only quantizes numerator sums.

// Phase 1a: R7-style LDS chain build (CAS + exch only, no float atomics),
// staging w per (point,vertex) and q per point in LDS (stride-5 = odd ->
// spreads banks during the divergent chain walk).
// Phase 1b: per distinct cell, ONE thread walks the local chain with plain
// LDS reads, sums the 5 channels, emits ONE 16B node + one global exch splice.
__global__ void k_build_hyb(const float* __restrict__ image,
                            const float* __restrict__ input_,
                            int* __restrict__ head,
                            int4* __restrict__ nodes)
{
  __shared__ int   ls_cell[LHS];
  __shared__ int   ls_head[LHS];
  __shared__ int   ls_next[1280];
  __shared__ float ls_w[1280];
  __shared__ float ls_q[256 * 5];     // stride 5 (odd) -> conflict-light
  __shared__ int   ls_cnt;

  int tid = threadIdx.x;
  #pragma unroll
  for (int i = 0; i < LHS / 256; i++){
    ls_cell[tid + 256 * i] = -1;
    ls_head[tid + 256 * i] = -1;
  }
  if (tid == 0) ls_cnt = 0;
  __syncthreads();

  int n = blockIdx.x * 256 + tid;
  ls_q[tid * 5 + 0] = input_[n];
  ls_q[tid * 5 + 1] = input_[NPTS + n];
  ls_q[tid * 5 + 2] = input_[2 * NPTS + n];
  ls_q[tid * 5 + 3] = input_[3 * NPTS + n];
  LatPt P = lat_compute(n, image[n]);

  #pragma unroll
  for (int r = 0; r < 5; r++){
    int cell = P.cell[r];
    unsigned int h = ((unsigned int)cell * 2654435761u) & (LHS - 1);
    while (true){
      int prev = atomicCAS(&ls_cell[h], -1, cell);
      if (prev == -1 || prev == cell) break;
      h = (h + 1) & (LHS - 1);
    }
    int e = tid * 5 + r;
    ls_w[e] = P.w[r];
    ls_next[e] = atomicExch(&ls_head[h], e);   // local chain push
  }
  __syncthreads();

  int blockBase = blockIdx.x * 1280;
  for (int i = tid; i < LHS; i += 256){
    int cell = ls_cell[i];
    if (cell < 0) continue;
    float s0 = 0.f, s1 = 0.f, s2 = 0.f, s3 = 0.f, s4 = 0.f;
    int e = ls_head[i];
    while (e >= 0){
      float w = ls_w[e];
      int pt = e / 5;
      s0 += w * ls_q[pt * 5 + 0];
      s1 += w * ls_q[pt * 5 + 1];
      s2 += w * ls_q[pt * 5 + 2];
      s3 += w * ls_q[pt * 5 + 3];
      s4 += w;
      e = ls_next[e];
    }
    int li = atomicAdd(&ls_cnt, 1);      // LDS counter: compact node index
    int node = blockBase + li;
    int old = atomicExch(&head[cell], node);
    __half2 h01 = __floats2half2_rn(s0, s1);
    __half2 h23 = __floats2half2_rn(s2, s3);
    int4 raw;
    raw.x = old;
    raw.y = *reinterpret_cast<int*>(&h01);
    raw.z = *reinterpret_cast<int*>(&h23);
    raw.w = __float_as_int(s4);
    nodes[node] = raw;                   // single 16B store
  }
}

// Phase 2: gather — walk short pre-summed node chains; ONE 16B load per hop.
// Emits occupancy bitmap via wave ballot.
__global__ void k_gather_agg(const int* __restrict__ head,
                             const int4* __restrict__ nodes,
                             float* __restrict__ vals,
                             unsigned int* __restrict__ bitmap)
{
  int c = blockIdx.x * blockDim.x + threadIdx.x;
  int e = -1;
  if (c < GCELLS1) e = head[c];
  bool occ = (e >= 0);
  unsigned long long mask = __ballot(occ);
  int lane = threadIdx.x & 63;
  if (lane == 0)       bitmap[c >> 5] = (unsigned int)(mask & 0xffffffffu);
  else if (lane == 32) bitmap[c >> 5] = (unsigned int)(mask >> 32);
  if (c >= GCELLS1) return;

  float s0 = 0.f, s1 = 0.f, s2 = 0.f, s3 = 0.f, s4 = 0.f;
  while (e >= 0){
    int4 raw = nodes[e];                 // one 16B load: next+q01+q23+w4
    __half2 h01 = *reinterpret_cast<__half2*>(&raw.y);
    __half2 h23 = *reinterpret_cast<__half2*>(&raw.z);
    float2 f01 = __half22float2(h01);
    float2 f23 = __half22float2(h23);
    s0 += f01.x; s1 += f01.y; s2 += f23.x; s3 += f23.y;
    s4 += __int_as_float(raw.w);
    e = raw.x;
  }
  float* v = vals + (size_t)c * 5;
  v[0] = s0; v[1] = s1; v[2] = s2; v[3] = s3; v[4] = s4;
}

// ====================== PATH B (fallback): R8 scheme ======================

__global__ void k_build_lds(const float* __restrict__ image,
                            int* __restrict__ head,
                            BN* __restrict__ bnext)
{
  __shared__ int ls_cell[LHS];
  __shared__ int ls_head[LHS];

  int tid = threadIdx.x;
  #pragma unroll
  for (int i = 0; i < LHS / 256; i++){
    ls_cell[tid + 256 * i] = -1;
    ls_head[tid + 256 * i] = -1;
  }
  __syncthreads();

  int n = blockIdx.x * 256 + tid;
  LatPt P = lat_compute(n, image[n]);
  int blockBase = blockIdx.x * 1280;

  int lold[5]; unsigned int hs[5];
  #pragma unroll
  for (int r = 0; r < 5; r++){
    int cell = P.cell[r];
    unsigned int h = ((unsigned int)cell * 2654435761u) & (LHS - 1);
    while (true){
      int prev = atomicCAS(&ls_cell[h], -1, cell);
      if (prev == -1 || prev == cell) break;
      h = (h + 1) & (LHS - 1);
    }
    hs[r] = h;
    lold[r] = atomicExch(&ls_head[h], tid * 5 + r);
  }
  __syncthreads();

  #pragma unroll
  for (int r = 0; r < 5; r++){
    int e = blockBase + tid * 5 + r;
    int nxt2;
    if (lold[r] < 0){
      int lhead = ls_head[hs[r]];
      nxt2 = atomicExch(&head[P.cell[r]], blockBase + lhead);
    } else {
      nxt2 = blockBase + lold[r];
    }
    BN bn; bn.w = P.w[r]; bn.next = nxt2;
    bnext[e] = bn;
  }
}

__global__ void k_gather_d(const int* __restrict__ head,
                           const BN* __restrict__ bnext,
                           const float4* __restrict__ qp,
                           float* __restrict__ vals,
                           unsigned int* __restrict__ bitmap)
{
  int c = blockIdx.x * blockDim.x + threadIdx.x;
  int e = -1;
  if (c < GCELLS1) e = head[c];
  bool occ = (e >= 0);
  unsigned long long mask = __ballot(occ);
  int lane = threadIdx.x & 63;
  if (lane == 0)       bitmap[c >> 5] = (unsigned int)(mask & 0xffffffffu);
  else if (lane == 32) bitmap[c >> 5] = (unsigned int)(mask >> 32);
  if (c >= GCELLS1) return;

  float s0 = 0.f, s1 = 0.f, s2 = 0.f, s3 = 0.f, s4 = 0.f;
  while (e >= 0){
    BN bn = bnext[e];
    float4 q = qp[e / 5];
    s0 += bn.w * q.x; s1 += bn.w * q.y; s2 += bn.w * q.z; s3 += bn.w * q.w; s4 += bn.w;
    e = bn.next;
  }
  float* v = vals + (size_t)c * 5;
  v[0] = s0; v[1] = s1; v[2] = s2; v[3] = s3; v[4] = s4;
}

// ====================== SHARED: blur + slice ======================

__global__ void k_blur_d(const unsigned int* __restrict__ bitmap,
                         const float* __restrict__ vin,
                         float* __restrict__ vout,
                         int dPa, int dPb, int dMa, int dMb, int zfill)
{
  int c = blockIdx.x * blockDim.x + threadIdx.x;
  if (c >= GCELLS) return;
  unsigned int w = bitmap[c >> 5];
  if (!((w >> (c & 31)) & 1u)){
    if (zfill){
      float* vo = vout + (size_t)c * 5;
      vo[0] = 0.f; vo[1] = 0.f; vo[2] = 0.f; vo[3] = 0.f; vo[4] = 0.f;
    }
    return;
  }
  int r = c % 5;
  int p1 = c + (r == 4 ? dPb : dPa);
  int p2 = c + (r == 0 ? dMb : dMa);
  float* vo = vout + (size_t)c * 5;
  const float* va = vin + (size_t)c * 5;
  const float* n1 = vin + (size_t)p1 * 5;  // empty neighbors hold zeros
  const float* n2 = vin + (size_t)p2 * 5;
  #pragma unroll
  for (int ch = 0; ch < 5; ch++)
    vo[ch] = 0.5f * va[ch] + 0.25f * (n1[ch] + n2[ch]);
}

__global__ void k_slice_d(const float* __restrict__ image,
                          const float* __restrict__ vals,
                          float* __restrict__ out)
{
  int n = blockIdx.x * blockDim.x + threadIdx.x;
  if (n >= NPTS) return;
  LatPt P = lat_compute(n, image[n]);

  float s0 = 0.f, s1 = 0.f, s2 = 0.f, s3 = 0.f, s4 = 0.f;
  #pragma unroll
  for (int r = 0; r < 5; r++){
    float w = P.w[r];
    const float* v = vals + (size_t)P.cell[r] * 5;
    s0 += w * v[0]; s1 += w * v[1]; s2 += w * v[2]; s3 += w * v[3]; s4 += w * v[4];
  }
  float denom = s4 + 2.2204460492503131e-16f;
  out[n]            = s0 / denom;
  out[NPTS + n]     = s1 / denom;
  out[2 * NPTS + n] = s2 / denom;
  out[3 * NPTS + n] = s3 / denom;
}

// ============================ HOST ============================

extern "C" void kernel_launch(void* const* d_in, const int* in_sizes, int n_in,
                              void* d_out, int out_size, void* d_ws, size_t ws_size,
                              hipStream_t stream)
{
  const float* input_ = (const float*)d_in[0];
  const float* image  = (const float*)d_in[1];
  float* out = (float*)d_out;
  char* ws = (char*)d_ws;

  const int NB = (NPTS + 255) / 256;
  const int CB = (GCELLS1 + 255) / 256;
  const size_t BMWORDS = (size_t)CB * 8;
  const int Sj[5] = { GS0, GS1, GS2, GS3, 0 };

  // ---- Path A workspace (~161 MB): layout = bitmap | head | nodes | valsA.
  // valsB ALIASED over head+nodes (14.8+71 = 85.8 MB >= 74.2 needed): head
  // and nodes are dead after k_gather_agg; blur j=0 zfills valsB's empties.
  {
    size_t o = 0;
    size_t off_bm   = o; o += BMWORDS * 4;              o = (o + 255) & ~(size_t)255;
    size_t off_dead = o;                                 // head+nodes region
    size_t off_head = o; o += (size_t)GCELLS1 * 4;      o = (o + 255) & ~(size_t)255;
    size_t off_node = o; o += (size_t)NP5 * 16;         o = (o + 255) & ~(size_t)255;
    size_t dead_end = o;
    size_t off_vA   = o; o += (size_t)GCELLS1 * 5 * 4;
    size_t vB_need  = (size_t)GCELLS1 * 5 * 4;
    size_t off_vB   = off_dead;
    size_t need = o;
    if (dead_end - off_dead < vB_need){ off_vB = o; need = o + vB_need; } // paranoia
    if (need <= ws_size){
      unsigned int* bitmap = (unsigned int*)(ws + off_bm);
      int*          head   = (int*)(ws + off_head);
      int4*         nodes  = (int4*)(ws + off_node);
      float*        valsA  = (float*)(ws + off_vA);
      float*        valsB  = (float*)(ws + off_vB);

      hipMemsetAsync(head, 0xFF, (size_t)GCELLS1 * 4, stream);

      k_build_hyb<<<NB, 256, 0, stream>>>(image, input_, head, nodes);
      k_gather_agg<<<CB, 256, 0, stream>>>(head, nodes, valsA, bitmap);

      float* vin = valsA; float* vout = valsB;
      for (int j = 0; j < 5; j++){
        int dPa = 1 - Sj[j];
        int dPb = GSSUM - Sj[j] - 4;
        int dMa = Sj[j] - 1;
        int dMb = Sj[j] - GSSUM + 4;
        k_blur_d<<<CB, 256, 0, stream>>>(bitmap, vin, vout, dPa, dPb, dMa, dMb,
                                         (j == 0) ? 1 : 0);
        float* t = vin; vin = vout; vout = t;
      }

      k_slice_d<<<NB, 256, 0, stream>>>(image, vin, out);
      return;
    }
  }

  // ---- Path B fallback: R8 per-entry chains (all-fp32) ----
  size_t o = 0;
  size_t off_head  = o; o += (size_t)GCELLS1 * 4;      o = (o + 255) & ~(size_t)255;
  size_t off_bm    = o; o += BMWORDS * 4;              o = (o + 255) & ~(size_t)255;
  size_t off_bnext = o; o += (size_t)NP5 * 8;          o = (o + 255) & ~(size_t)255;
  size_t off_qp    = o; o += (size_t)NPTS * 16;        o = (o + 255) & ~(size_t)255;
  size_t off_vA    = o; o += (size_t)GCELLS1 * 5 * 4;  o = (o + 255) & ~(size_t)255;
  size_t off_vB    = o; o += (size_t)GCELLS1 * 5 * 4;

  int*          head   = (int*)(ws + off_head);
  unsigned int* bitmap = (unsigned int*)(ws + off_bm);
  BN*           bnext  = (BN*)(ws + off_bnext);
  float4*       qp     = (float4*)(ws + off_qp);
  float*        valsA  = (float*)(ws + off_vA);
  float*        valsB  = (float*)(ws + off_vB);

  hipMemsetAsync(head, 0xFF, (size_t)GCELLS1 * 4, stream);

  k_qpack<<<NB, 256, 0, stream>>>(input_, qp);
  k_build_lds<<<NB, 256, 0, stream>>>(image, head, bnext);
  k_gather_d<<<CB, 256, 0, stream>>>(head, bnext, qp, valsA, bitmap);

  float* vin = valsA; float* vout = valsB;
  for (int j = 0; j < 5; j++){
    int dPa = 1 - Sj[j];
    int dPb = GSSUM - Sj[j] - 4;
    int dMa = Sj[j] - 1;
    int dMb = Sj[j] - GSSUM + 4;
    k_blur_d<<<CB, 256, 0, stream>>>(bitmap, vin, vout, dPa, dPb, dMa, dMb,
                                     (j == 0) ? 1 : 0);
    float* t = vin; vin = vout; vout = t;
  }

  k_slice_d<<<NB, 256, 0, stream>>>(image, vin, out);
}

// Round 13
// 211.291 us; speedup vs baseline: 1.5819x; 1.0604x over previous
//
#include <hip/hip_runtime.h>
#include <hip/hip_fp16.h>
#include <stdint.h>

#define NPTS (96*96*96)          // 884736
#define NP5  (NPTS*5)            // 4423680 entries (point,vertex)

// Dense lattice grid (interval arithmetic from fixed domain: z,y,x in [0,95],
// image in [0,1); incl. rank-adjust, r-offset, blur padding, +/-2 margin):
//   q0 in [-3,25], q1 in [-14,14], q2 in [-16,8], q3 in [-17,3]
#define GD1 33
#define GD2 29
#define GD3 25
#define GO0 5
#define GO1 16
#define GO2 18
#define GO3 19
#define GS3 5
#define GS2 (GD3*GS3)      // 125
#define GS1 (GD2*GS2)      // 3625
#define GS0 (GD1*GS1)      // 119625
#define GCELLS (31*GS0)    // 3708375
#define GCELLS1 (GCELLS+1) // + trash cell for (never-expected) OOB
#define GSSUM (GS0+GS1+GS2+GS3)  // 123380

#define LHS 2048           // block-local LDS hash slots (1280 entries -> load <=0.625)

struct LatPt { int cell[5]; float w[5]; };

// Per-cell value record: 12B. Numerator channels fp16 (rounded per pass),
// denominator w4 fp32 (exact through the whole blur chain).
// Accessed as int3 (4B aligned, dwordx3 loads/stores).

// Shared per-point lattice math macro producing rank[5], rem0i[4], b[]
#define LATTICE_MATH(n)                                                        \
  int x = n % 96, y = (n / 96) % 96, z = n / (96 * 96);                        \
  float cf[4];                                                                 \
  cf[0] = ((float)z / 5.0f) * 2.8867513459481287f;                             \
  cf[1] = ((float)y / 5.0f) * 1.6666666666666667f;                             \
  cf[2] = ((float)x / 5.0f) * 1.1785113019775793f;                             \
  cf[3] = (imgv / 0.25f) * 0.9128709291752769f;                                \
  float elev[5];                                                               \
  float sm = 0.f;                                                              \
  _Pragma("unroll")                                                            \
  for (int i = 4; i >= 1; --i){ float c = cf[i-1]; elev[i] = sm - (float)i * c; sm += c; } \
  elev[0] = sm;                                                                \
  float rem0[5]; float sumrd_f = 0.f;                                          \
  _Pragma("unroll")                                                            \
  for (int i = 0; i < 5; i++){ float rd = rintf(elev[i] / 5.0f); rem0[i] = rd * 5.0f; sumrd_f += rd; } \
  int sum_rd = (int)sumrd_f;                                                   \
  float diff[5];                                                               \
  _Pragma("unroll")                                                            \
  for (int i = 0; i < 5; i++) diff[i] = elev[i] - rem0[i];                     \
  int rank[5];                                                                 \
  _Pragma("unroll")                                                            \
  for (int i = 0; i < 5; i++){                                                 \
    int r = 0;                                                                 \
    _Pragma("unroll")                                                          \
    for (int j = 0; j < 5; j++){                                               \
      r += (diff[j] > diff[i] || (diff[j] == diff[i] && j < i)) ? 1 : 0;       \
    }                                                                          \
    rank[i] = r + sum_rd;                                                      \
  }                                                                            \
  _Pragma("unroll")                                                            \
  for (int i = 0; i < 5; i++){                                                 \
    if (rank[i] < 0)      { rank[i] += 5; rem0[i] += 5.0f; }                   \
    else if (rank[i] > 4) { rank[i] -= 5; rem0[i] -= 5.0f; }                   \
  }                                                                            \
  float b[6] = {0.f,0.f,0.f,0.f,0.f,0.f};                                      \
  _Pragma("unroll")                                                            \
  for (int i = 0; i < 5; i++){                                                 \
    float v = (elev[i] - rem0[i]) / 5.0f;                                      \
    b[4 - rank[i]] += v;                                                       \
    b[5 - rank[i]] -= v;                                                       \
  }                                                                            \
  b[0] += 1.0f + b[5];                                                         \
  int rem0i[4];                                                                \
  _Pragma("unroll")                                                            \
  for (int i = 0; i < 4; i++) rem0i[i] = (int)rem0[i];

// Dense-path per-point result (shared by build & slice — bit-identical math).
__device__ __forceinline__ LatPt lat_compute(int n, float imgv)
{
  LATTICE_MATH(n)
  LatPt p;
  #pragma unroll
  for (int r = 0; r < 5; r++){
    int q0 = (rem0i[0] / 5) - (rank[0] < 5 - r ? 0 : 1) + GO0;
    int q1 = (rem0i[1] / 5) - (rank[1] < 5 - r ? 0 : 1) + GO1;
    int q2 = (rem0i[2] / 5) - (rank[2] < 5 - r ? 0 : 1) + GO2;
    int q3 = (rem0i[3] / 5) - (rank[3] < 5 - r ? 0 : 1) + GO3;
    int cell = (((q0 * GD1 + q1) * GD2 + q2) * GD3 + q3) * 5 + r;
    if ((unsigned)cell >= (unsigned)GCELLS) cell = GCELLS;
    p.cell[r] = cell;
    p.w[r] = b[r];
  }
  return p;
}

// Phase 1: hybrid chain-build + LDS-walk aggregation. Node = ONE 16B record
// { next:int, q01:half2, q23:half2, w4:float }. ls_q stride-4 (16B aligned)
// so the chain walk's 4 channel reads fuse into one ds_read_b128.
__global__ void k_build_hyb(const float* __restrict__ image,
                            const float* __restrict__ input_,
                            int* __restrict__ head,
                            int4* __restrict__ nodes)
{
  __shared__ int   ls_cell[LHS];
  __shared__ int   ls_head[LHS];
  __shared__ int   ls_next[1280];
  __shared__ float ls_w[1280];
  __shared__ float ls_q[256 * 4];     // stride 4 -> ds_read_b128 in the walk
  __shared__ int   ls_cnt;

  int tid = threadIdx.x;
  #pragma unroll
  for (int i = 0; i < LHS / 256; i++){
    ls_cell[tid + 256 * i] = -1;
    ls_head[tid + 256 * i] = -1;
  }
  if (tid == 0) ls_cnt = 0;
  __syncthreads();

  int n = blockIdx.x * 256 + tid;
  ls_q[tid * 4 + 0] = input_[n];
  ls_q[tid * 4 + 1] = input_[NPTS + n];
  ls_q[tid * 4 + 2] = input_[2 * NPTS + n];
  ls_q[tid * 4 + 3] = input_[3 * NPTS + n];
  LatPt P = lat_compute(n, image[n]);

  #pragma unroll
  for (int r = 0; r < 5; r++){
    int cell = P.cell[r];
    unsigned int h = ((unsigned int)cell * 2654435761u) & (LHS - 1);
    while (true){
      int prev = atomicCAS(&ls_cell[h], -1, cell);
      if (prev == -1 || prev == cell) break;
      h = (h + 1) & (LHS - 1);
    }
    int e = tid * 5 + r;
    ls_w[e] = P.w[r];
    ls_next[e] = atomicExch(&ls_head[h], e);   // local chain push
  }
  __syncthreads();

  int blockBase = blockIdx.x * 1280;
  for (int i = tid; i < LHS; i += 256){
    int cell = ls_cell[i];
    if (cell < 0) continue;
    float s0 = 0.f, s1 = 0.f, s2 = 0.f, s3 = 0.f, s4 = 0.f;
    int e = ls_head[i];
    while (e >= 0){
      float w = ls_w[e];
      int pt = e / 5;
      s0 += w * ls_q[pt * 4 + 0];
      s1 += w * ls_q[pt * 4 + 1];
      s2 += w * ls_q[pt * 4 + 2];
      s3 += w * ls_q[pt * 4 + 3];
      s4 += w;
      e = ls_next[e];
    }
    int li = atomicAdd(&ls_cnt, 1);      // LDS counter: compact node index
    int node = blockBase + li;
    int old = atomicExch(&head[cell], node);
    __half2 h01 = __floats2half2_rn(s0, s1);
    __half2 h23 = __floats2half2_rn(s2, s3);
    int4 raw;
    raw.x = old;
    raw.y = *reinterpret_cast<int*>(&h01);
    raw.z = *reinterpret_cast<int*>(&h23);
    raw.w = __float_as_int(s4);
    nodes[node] = raw;                   // single 16B store
  }
}

// Phase 2: gather — walk pre-summed node chains (one 16B load per hop);
// write the 12B cell record; emit occupancy bitmap via wave ballot.
__global__ void k_gather_agg(const int* __restrict__ head,
                             const int4* __restrict__ nodes,
                             int3* __restrict__ vals,
                             unsigned int* __restrict__ bitmap)
{
  int c = blockIdx.x * blockDim.x + threadIdx.x;
  int e = -1;
  if (c < GCELLS1) e = head[c];
  bool occ = (e >= 0);
  unsigned long long mask = __ballot(occ);
  int lane = threadIdx.x & 63;
  if (lane == 0)       bitmap[c >> 5] = (unsigned int)(mask & 0xffffffffu);
  else if (lane == 32) bitmap[c >> 5] = (unsigned int)(mask >> 32);
  if (c >= GCELLS1) return;

  float s0 = 0.f, s1 = 0.f, s2 = 0.f, s3 = 0.f, s4 = 0.f;
  while (e >= 0){
    int4 raw = nodes[e];                 // one 16B load: next+q01+q23+w4
    __half2 h01 = *reinterpret_cast<__half2*>(&raw.y);
    __half2 h23 = *reinterpret_cast<__half2*>(&raw.z);
    float2 f01 = __half22float2(h01);
    float2 f23 = __half22float2(h23);
    s0 += f01.x; s1 += f01.y; s2 += f23.x; s3 += f23.y;
    s4 += __int_as_float(raw.w);
    e = raw.x;
  }
  __half2 o01 = __floats2half2_rn(s0, s1);
  __half2 o23 = __floats2half2_rn(s2, s3);
  int3 rec;
  rec.x = *reinterpret_cast<int*>(&o01);
  rec.y = *reinterpret_cast<int*>(&o23);
  rec.z = __float_as_int(s4);
  vals[c] = rec;
}

// Phase 3: blur pass over 12B records. Numerators fp16 (computed fp32),
// w4 fp32 exact. zfill=1 only on pass 1 (ping-pong invariant).
__global__ void k_blur_d(const unsigned int* __restrict__ bitmap,
                         const int3* __restrict__ vin,
                         int3* __restrict__ vout,
                         int dPa, int dPb, int dMa, int dMb, int zfill)
{
  int c = blockIdx.x * blockDim.x + threadIdx.x;
  if (c >= GCELLS) return;
  unsigned int w = bitmap[c >> 5];
  if (!((w >> (c & 31)) & 1u)){
    if (zfill){
      int3 zero; zero.x = 0; zero.y = 0; zero.z = 0;
      vout[c] = zero;
    }
    return;
  }
  int r = c % 5;
  int p1 = c + (r == 4 ? dPb : dPa);
  int p2 = c + (r == 0 ? dMb : dMa);
  int3 a  = vin[c];
  int3 b1 = vin[p1];   // empty neighbors hold zero records
  int3 b2 = vin[p2];

  float2 a01 = __half22float2(*reinterpret_cast<__half2*>(&a.x));
  float2 a23 = __half22float2(*reinterpret_cast<__half2*>(&a.y));
  float  aw  = __int_as_float(a.z);
  float2 m01 = __half22float2(*reinterpret_cast<__half2*>(&b1.x));
  float2 m23 = __half22float2(*reinterpret_cast<__half2*>(&b1.y));
  float  mw  = __int_as_float(b1.z);
  float2 n01 = __half22float2(*reinterpret_cast<__half2*>(&b2.x));
  float2 n23 = __half22float2(*reinterpret_cast<__half2*>(&b2.y));
  float  nw  = __int_as_float(b2.z);

  float o0 = 0.5f * a01.x + 0.25f * (m01.x + n01.x);
  float o1 = 0.5f * a01.y + 0.25f * (m01.y + n01.y);
  float o2 = 0.5f * a23.x + 0.25f * (m23.x + n23.x);
  float o3 = 0.5f * a23.y + 0.25f * (m23.y + n23.y);
  float ow = 0.5f * aw    + 0.25f * (mw    + nw);

  __half2 o01 = __floats2half2_rn(o0, o1);
  __half2 o23 = __floats2half2_rn(o2, o3);
  int3 rec;
  rec.x = *reinterpret_cast<int*>(&o01);
  rec.y = *reinterpret_cast<int*>(&o23);
  rec.z = __float_as_int(ow);
  vout[c] = rec;
}

// Phase 4: slice + normalize — recomputes cells & weights via lat_compute.
__global__ void k_slice_d(const float* __restrict__ image,
                          const int3* __restrict__ vals,
                          float* __restrict__ out)
{
  int n = blockIdx.x * blockDim.x + threadIdx.x;
  if (n >= NPTS) return;
  LatPt P = lat_compute(n, image[n]);

  float s0 = 0.f, s1 = 0.f, s2 = 0.f, s3 = 0.f, s4 = 0.f;
  #pragma unroll
  for (int r = 0; r < 5; r++){
    float w = P.w[r];
    int3 rec = vals[P.cell[r]];
    float2 f01 = __half22float2(*reinterpret_cast<__half2*>(&rec.x));
    float2 f23 = __half22float2(*reinterpret_cast<__half2*>(&rec.y));
    s0 += w * f01.x; s1 += w * f01.y; s2 += w * f23.x; s3 += w * f23.y;
    s4 += w * __int_as_float(rec.z);
  }
  float denom = s4 + 2.2204460492503131e-16f;
  out[n]            = s0 / denom;
  out[NPTS + n]     = s1 / denom;
  out[2 * NPTS + n] = s2 / denom;
  out[3 * NPTS + n] = s3 / denom;
}

// ============================ HOST ============================

extern "C" void kernel_launch(void* const* d_in, const int* in_sizes, int n_in,
                              void* d_out, int out_size, void* d_ws, size_t ws_size,
                              hipStream_t stream)
{
  const float* input_ = (const float*)d_in[0];
  const float* image  = (const float*)d_in[1];
  float* out = (float*)d_out;
  char* ws = (char*)d_ws;

  const int NB = (NPTS + 255) / 256;
  const int CB = (GCELLS1 + 255) / 256;
  const size_t BMWORDS = (size_t)CB * 8;
  const int Sj[5] = { GS0, GS1, GS2, GS3, 0 };

  // Workspace (~131 MB aliased): bitmap | head | nodes | valsA.
  // valsB ALIASED over head+nodes (14.8+70.8 MB >= 44.5 needed): both dead
  // after k_gather_agg; blur j=0 zfills valsB's empty cells.
  size_t o = 0;
  size_t off_bm   = o; o += BMWORDS * 4;              o = (o + 255) & ~(size_t)255;
  size_t off_dead = o;                                 // head+nodes region
  size_t off_head = o; o += (size_t)GCELLS1 * 4;      o = (o + 255) & ~(size_t)255;
  size_t off_node = o; o += (size_t)NP5 * 16;         o = (o + 255) & ~(size_t)255;
  size_t dead_end = o;
  size_t off_vA   = o; o += (size_t)GCELLS1 * 12;
  size_t vB_need  = (size_t)GCELLS1 * 12;
  size_t off_vB   = off_dead;
  if (dead_end - off_dead < vB_need || o + 0 > ws_size){
    // non-aliased fallback layout (~176 MB)
    off_vB = (o + 255) & ~(size_t)255;
  }

  unsigned int* bitmap = (unsigned int*)(ws + off_bm);
  int*          head   = (int*)(ws + off_head);
  int4*         nodes  = (int4*)(ws + off_node);
  int3*         valsA  = (int3*)(ws + off_vA);
  int3*         valsB  = (int3*)(ws + off_vB);

  hipMemsetAsync(head, 0xFF, (size_t)GCELLS1 * 4, stream);

  k_build_hyb<<<NB, 256, 0, stream>>>(image, input_, head, nodes);
  k_gather_agg<<<CB, 256, 0, stream>>>(head, nodes, valsA, bitmap);

  int3* vin = valsA; int3* vout = valsB;
  for (int j = 0; j < 5; j++){
    int dPa = 1 - Sj[j];
    int dPb = GSSUM - Sj[j] - 4;
    int dMa = Sj[j] - 1;
    int dMb = Sj[j] - GSSUM + 4;
    k_blur_d<<<CB, 256, 0, stream>>>(bitmap, vin, vout, dPa, dPb, dMa, dMb,
                                     (j == 0) ? 1 : 0);
    int3* t = vin; vin = vout; vout = t;
  }

  k_slice_d<<<NB, 256, 0, stream>>>(image, vin, out);
}